// Round 10
// baseline (385.873 us; speedup 1.0000x reference)
//
#include <hip/hip_runtime.h>
#include <hip/hip_bf16.h>

#define N_NODES 50000
#define N_EDGES 800000
#define IN_F 256
#define OUT_F 64

#define NBKT 256        // dst-range buckets == CU count; 196 dsts each
#define DST_PER_BKT 196 // 196*256 = 50176 >= 50000
#define BKT_CAP 3584    // mean 3125, sigma ~56 -> +8.2 sigma; multiple of 64

typedef __attribute__((ext_vector_type(8))) short short8;   // 8 bf16 (4 VGPRs)
typedef __attribute__((ext_vector_type(4))) float f32x4;    // MFMA acc

static __device__ __forceinline__ ushort f2bf(float v) {
    __hip_bfloat16 b = __float2bfloat16(v);
    return *(ushort*)&b;
}

// ---------------- prep: zero bucket cursors + W -> bf16 B-fragment order ----
__global__ __launch_bounds__(256) void gc_prep(const float* __restrict__ W,
                                               ushort* __restrict__ Wb,
                                               int* __restrict__ cursor) {
    const int g = blockIdx.x * 256 + threadIdx.x;  // 8 blocks -> g in [0,2048)
    if (g < NBKT) cursor[g] = 0;
    {
        const int s = g >> 9;
        const int kk = (g >> 6) & 7;
        const int lane = g & 63;
        const int n = s * 16 + (lane & 15);
        const int kb = kk * 32 + (lane >> 4) * 8;
#pragma unroll
        for (int j = 0; j < 8; ++j)
            Wb[(size_t)g * 8 + j] = f2bf(W[(kb + j) * OUT_F + n]);
    }
}

// ---------------- fused mid: blocks [0,391) bucket, [391,1954) gemm ---------
// bucket (edge partition) and gemm (x-stream MFMA) are independent; one grid
// overlaps them (R1/R8 role-split pattern).
__global__ __launch_bounds__(256) void gc_mid(const float* __restrict__ x,
                                              const ushort* __restrict__ Wb,
                                              ushort* __restrict__ h,
                                              const int* __restrict__ esrc,
                                              const int* __restrict__ edst,
                                              const float* __restrict__ ew,
                                              int* __restrict__ cursor,
                                              uint2* __restrict__ arena) {
    __shared__ ushort xs[32 * 264];  // 16896 B (gemm role)
    __shared__ int hist[NBKT];       // 1 KB (bucket role)
    __shared__ int base[NBKT];
    const int t = threadIdx.x;

    if (blockIdx.x < 391) {
        // ---- bucket: partition 2048 edges into 256 dst-range lists ----
        if (t < NBKT) hist[t] = 0;
        __syncthreads();

        const int e0 = blockIdx.x * 2048 + t * 8;  // N_EDGES % 8 == 0
        const bool valid = e0 < N_EDGES;
        int b[8], loff[8];
        uint2 ent[8];
        if (valid) {
            const int4 sa = *(const int4*)(esrc + e0);
            const int4 sb = *(const int4*)(esrc + e0 + 4);
            const int4 da = *(const int4*)(edst + e0);
            const int4 db = *(const int4*)(edst + e0 + 4);
            const float4 wa = *(const float4*)(ew + e0);
            const float4 wb = *(const float4*)(ew + e0 + 4);
            const int ds[8] = {da.x, da.y, da.z, da.w, db.x, db.y, db.z, db.w};
            const int ss[8] = {sa.x, sa.y, sa.z, sa.w, sb.x, sb.y, sb.z, sb.w};
            const float wf[8] = {wa.x, wa.y, wa.z, wa.w, wb.x, wb.y, wb.z, wb.w};
#pragma unroll
            for (int j = 0; j < 8; ++j) {
                b[j] = ds[j] / DST_PER_BKT;  // exact magic-mul
                ent[j].x = (unsigned)ds[j];
                ent[j].y = ((unsigned)f2bf(wf[j]) << 16) | (unsigned)(ss[j] & 0xFFFF);
                loff[j] = atomicAdd(&hist[b[j]], 1);
            }
        }
        __syncthreads();
        if (t < NBKT) {
            const int hc = hist[t];
            base[t] = hc ? atomicAdd(&cursor[t], hc) : 0;
        }
        __syncthreads();
        if (valid) {
#pragma unroll
            for (int j = 0; j < 8; ++j) {
                const int pos = base[b[j]] + loff[j];
                if (pos < BKT_CAP)  // ~8-sigma insurance against slice overflow
                    arena[(size_t)b[j] * BKT_CAP + pos] = ent[j];
            }
        }
        return;
    }

    // ---- gemm: 32-node MFMA tile ----
    const int nbase = (blockIdx.x - 391) * 32;  // 1563 tiles
    {
#pragma unroll
        for (int i = 0; i < 8; ++i) {
            const int idx = t + i * 256;
            const int node = idx >> 6;
            const int c4 = idx & 63;
            int gnode = nbase + node;
            if (gnode >= N_NODES) gnode = N_NODES - 1;  // clamp tail loads
            const float4 v = ((const float4*)x)[(size_t)gnode * 64 + c4];
            ushort4 bv;
            bv.x = f2bf(v.x); bv.y = f2bf(v.y); bv.z = f2bf(v.z); bv.w = f2bf(v.w);
            *(ushort4*)&xs[node * 264 + c4 * 4] = bv;
        }
    }

    const int s = t >> 6;
    const int lane = t & 63;
    const int m = lane & 15;
    const int quad = lane >> 4;

    short8 bfrag[8];
#pragma unroll
    for (int kk = 0; kk < 8; ++kk)
        bfrag[kk] = *(const short8*)(Wb + ((size_t)(s * 8 + kk) * 64 + lane) * 8);

    __syncthreads();

    f32x4 acc0 = {0.f, 0.f, 0.f, 0.f};
    f32x4 acc1 = {0.f, 0.f, 0.f, 0.f};
#pragma unroll
    for (int kk = 0; kk < 8; ++kk) {
        const short8 a0 = *(const short8*)&xs[m * 264 + kk * 32 + quad * 8];
        const short8 a1 = *(const short8*)&xs[(16 + m) * 264 + kk * 32 + quad * 8];
        acc0 = __builtin_amdgcn_mfma_f32_16x16x32_bf16(a0, bfrag[kk], acc0, 0, 0, 0);
        acc1 = __builtin_amdgcn_mfma_f32_16x16x32_bf16(a1, bfrag[kk], acc1, 0, 0, 0);
    }

#pragma unroll
    for (int r = 0; r < 4; ++r) {
        const int row0 = nbase + quad * 4 + r;
        const int row1 = row0 + 16;
        if (row0 < N_NODES) h[(size_t)row0 * OUT_F + s * 16 + m] = f2bf(acc0[r]);
        if (row1 < N_NODES) h[(size_t)row1 * OUT_F + s * 16 + m] = f2bf(acc1[r]);
    }
}

// ---------------- accum: one block per bucket, LDS f32 accumulators ---------
// R9 post-mortem: atomicAdd(float*) on LDS lowers to a CAS retry loop (no
// unsafe-fp-atomics) -> serial dependency chain, VGPR_Count 12, 279us.
// unsafeAtomicAdd emits native fire-and-forget ds_add_f32: no return, no
// retry, and the 8-deep row-load batch can stay in flight again.
// Bank = feature%32 -> 2 lanes/bank, conflict-free. 196 dsts x 64 f32 = 50KB
// LDS; 256 blocks = 1/CU, 16 waves each.
__global__ __launch_bounds__(1024) void gc_accum(const ushort* __restrict__ h,
                                                 const uint2* __restrict__ arena,
                                                 const int* __restrict__ cursor,
                                                 const float* __restrict__ bias,
                                                 float* __restrict__ out) {
    __shared__ float acc[DST_PER_BKT * OUT_F];  // 50176 B
    const int b = blockIdx.x;
    const int t = threadIdx.x;
    const int f = t & 63;    // lane == feature
    const int wav = t >> 6;  // 0..15
    const int dbase = b * DST_PER_BKT;

    for (int i = t; i < DST_PER_BKT * OUT_F; i += 1024) acc[i] = 0.f;
    __syncthreads();

    const int n = min(cursor[b], BKT_CAP);
    const uint2* __restrict__ p = arena + (size_t)b * BKT_CAP;

    for (int i0 = wav * 64; i0 < n; i0 += 16 * 64) {
        // lane l holds entry i0+l (dummy with w=0 past n)
        const int idx = i0 + f;
        uint2 ent = {(unsigned)dbase, 0u};
        if (idx < n) ent = p[idx];

#pragma unroll
        for (int g = 0; g < 8; ++g) {
            unsigned ex[8], ey[8];
            ushort hv[8];
            // load phase: 8 independent coalesced 128B row loads, SGPR bases
#pragma unroll
            for (int j = 0; j < 8; ++j) {
                ex[j] = (unsigned)__builtin_amdgcn_readlane((int)ent.x, g * 8 + j);
                ey[j] = (unsigned)__builtin_amdgcn_readlane((int)ent.y, g * 8 + j);
                hv[j] = h[(size_t)(ey[j] & 0xFFFFu) * OUT_F + f];
            }
            // accumulate phase: native ds_add_f32, fire-and-forget
#pragma unroll
            for (int j = 0; j < 8; ++j) {
                const float w = __uint_as_float(ey[j] & 0xFFFF0000u);
                const float v = __uint_as_float((unsigned)hv[j] << 16);
                unsafeAtomicAdd(&acc[(ex[j] - (unsigned)dbase) * OUT_F + f], w * v);
            }
        }
    }
    __syncthreads();

    const float bf = bias[f];
    for (int i = t; i < DST_PER_BKT * OUT_F; i += 1024) {
        const int d = dbase + (i >> 6);
        if (d < N_NODES) out[(size_t)d * OUT_F + (i & 63)] = acc[i] + bf;
    }
}

extern "C" void kernel_launch(void* const* d_in, const int* in_sizes, int n_in,
                              void* d_out, int out_size, void* d_ws, size_t ws_size,
                              hipStream_t stream) {
    const float* x    = (const float*)d_in[0];
    const float* W    = (const float*)d_in[1];
    const float* bias = (const float*)d_in[2];
    const float* ew   = (const float*)d_in[3];
    const int* src    = (const int*)d_in[4];
    const int* dst    = (const int*)d_in[5];
    float* out = (float*)d_out;

    // workspace layout (16B-aligned); slots/cnt are gone entirely
    char* ws = (char*)d_ws;
    ushort* h    = (ushort*)ws;               // 6,400,000 B
    ushort* Wb   = (ushort*)(ws + 6400000);   // 32,768 B
    int* cursor  = (int*)(ws + 6432768);      // 1,024 B
    uint2* arena = (uint2*)(ws + 6433792);    // 7,340,032 B (total ~13.8 MB)

    gc_prep<<<8, 256, 0, stream>>>(W, Wb, cursor);
    // fused: blocks [0,391) bucket the edges, [391,1954) run the GEMM
    gc_mid<<<1954, 256, 0, stream>>>(x, Wb, h, src, dst, ew, cursor, arena);
    gc_accum<<<NBKT, 1024, 0, stream>>>(h, arena, cursor, bias, out);
}

// Round 11
// 158.541 us; speedup vs baseline: 2.4339x; 2.4339x over previous
//
#include <hip/hip_runtime.h>
#include <hip/hip_bf16.h>

#define N_NODES 50000
#define N_EDGES 800000
#define IN_F 256
#define OUT_F 64

#define CAP 64          // slot capacity per dst == wave width; max degree ~45
#define NBKT 128        // dst-range buckets
#define DST_PER_BKT 391 // ceil(50000/128)
#define BKT_CAP 6912    // mean 6250, sigma ~79 -> +8.4 sigma margin

typedef __attribute__((ext_vector_type(8))) short short8;   // 8 bf16 (4 VGPRs)
typedef __attribute__((ext_vector_type(4))) float f32x4;    // MFMA acc

static __device__ __forceinline__ ushort f2bf(float v) {
    __hip_bfloat16 b = __float2bfloat16(v);
    return *(ushort*)&b;
}

// ---------------- prep: zero bucket cursors + W -> bf16 B-fragment order ----
__global__ __launch_bounds__(256) void gc_prep(const float* __restrict__ W,
                                               ushort* __restrict__ Wb,
                                               int* __restrict__ cursor) {
    const int g = blockIdx.x * 256 + threadIdx.x;  // 8 blocks -> g in [0,2048)
    if (g < NBKT) cursor[g] = 0;
    {
        const int s = g >> 9;
        const int kk = (g >> 6) & 7;
        const int lane = g & 63;
        const int n = s * 16 + (lane & 15);
        const int kb = kk * 32 + (lane >> 4) * 8;
#pragma unroll
        for (int j = 0; j < 8; ++j)
            Wb[(size_t)g * 8 + j] = f2bf(W[(kb + j) * OUT_F + n]);
    }
}

// ---------------- bucket: partition edges into 128 dst-range lists ----------
// (R7-proven) contiguous per-block runs -> no write amplification.
__global__ __launch_bounds__(256) void gc_bucket(const int* __restrict__ esrc,
                                                 const int* __restrict__ edst,
                                                 const float* __restrict__ ew,
                                                 int* __restrict__ cursor,
                                                 uint2* __restrict__ arena) {
    __shared__ int hist[NBKT];
    __shared__ int base[NBKT];
    const int t = threadIdx.x;
    if (t < NBKT) hist[t] = 0;
    __syncthreads();

    const int e0 = blockIdx.x * 2048 + t * 8;  // 391 blocks; N_EDGES % 8 == 0
    const bool valid = e0 < N_EDGES;
    int b[8], loff[8];
    uint2 ent[8];
    if (valid) {
        const int4 sa = *(const int4*)(esrc + e0);
        const int4 sb = *(const int4*)(esrc + e0 + 4);
        const int4 da = *(const int4*)(edst + e0);
        const int4 db = *(const int4*)(edst + e0 + 4);
        const float4 wa = *(const float4*)(ew + e0);
        const float4 wb = *(const float4*)(ew + e0 + 4);
        const int ds[8] = {da.x, da.y, da.z, da.w, db.x, db.y, db.z, db.w};
        const int ss[8] = {sa.x, sa.y, sa.z, sa.w, sb.x, sb.y, sb.z, sb.w};
        const float wf[8] = {wa.x, wa.y, wa.z, wa.w, wb.x, wb.y, wb.z, wb.w};
#pragma unroll
        for (int j = 0; j < 8; ++j) {
            b[j] = ds[j] / DST_PER_BKT;  // exact magic-mul
            ent[j].x = (unsigned)ds[j];
            ent[j].y = ((unsigned)f2bf(wf[j]) << 16) | (unsigned)(ss[j] & 0xFFFF);
            loff[j] = atomicAdd(&hist[b[j]], 1);
        }
    }
    __syncthreads();
    if (t < NBKT) {
        const int hc = hist[t];
        base[t] = hc ? atomicAdd(&cursor[t], hc) : 0;
    }
    __syncthreads();
    if (valid) {
#pragma unroll
        for (int j = 0; j < 8; ++j) {
            const int pos = base[b[j]] + loff[j];
            if (pos < BKT_CAP)
                arena[(size_t)b[j] * BKT_CAP + pos] = ent[j];
        }
    }
}

// ---------------- place2: one block per bucket, LDS counting (R7-proven) ----
__global__ __launch_bounds__(512) void gc_place2(const uint2* __restrict__ arena,
                                                 const int* __restrict__ cursor,
                                                 int* __restrict__ cnt,
                                                 unsigned int* __restrict__ slots) {
    __shared__ int lcnt[DST_PER_BKT];
    const int b = blockIdx.x;
    const int t = threadIdx.x;
    const int dbase = b * DST_PER_BKT;

    for (int i = t; i < DST_PER_BKT; i += 512) lcnt[i] = 0;
    __syncthreads();

    const int n = min(cursor[b], BKT_CAP);
    const uint2* __restrict__ p = arena + (size_t)b * BKT_CAP;
    for (int i = t; i < n; i += 512) {
        const uint2 ent = p[i];
        const int pos = atomicAdd(&lcnt[ent.x - dbase], 1);
        if (pos < CAP) slots[(size_t)ent.x * CAP + pos] = ent.y;
    }
    __syncthreads();

    for (int i = t; i < DST_PER_BKT; i += 512) {
        const int d = dbase + i;
        if (d < N_NODES) cnt[d] = lcnt[i];
    }
}

// ---------------- gemm: 32-node MFMA tiles; h in SPLIT-HALF layout ----------
// h[half][node][32]: feature half = s>>1. Same bytes, same coalescing; lets
// gather work on a 3.2MB plane that fits a 4MiB XCD L2 (6.4MB did not).
__global__ __launch_bounds__(256) void gc_gemm(const float* __restrict__ x,
                                               const ushort* __restrict__ Wb,
                                               ushort* __restrict__ h) {
    __shared__ ushort xs[32 * 264];  // 16896 B
    const int t = threadIdx.x;
    const int nbase = blockIdx.x * 32;

    {
#pragma unroll
        for (int i = 0; i < 8; ++i) {
            const int idx = t + i * 256;
            const int node = idx >> 6;
            const int c4 = idx & 63;
            int gnode = nbase + node;
            if (gnode >= N_NODES) gnode = N_NODES - 1;  // clamp tail loads
            const float4 v = ((const float4*)x)[(size_t)gnode * 64 + c4];
            ushort4 bv;
            bv.x = f2bf(v.x); bv.y = f2bf(v.y); bv.z = f2bf(v.z); bv.w = f2bf(v.w);
            *(ushort4*)&xs[node * 264 + c4 * 4] = bv;
        }
    }

    const int s = t >> 6;
    const int lane = t & 63;
    const int m = lane & 15;
    const int quad = lane >> 4;

    short8 bfrag[8];
#pragma unroll
    for (int kk = 0; kk < 8; ++kk)
        bfrag[kk] = *(const short8*)(Wb + ((size_t)(s * 8 + kk) * 64 + lane) * 8);

    __syncthreads();

    f32x4 acc0 = {0.f, 0.f, 0.f, 0.f};
    f32x4 acc1 = {0.f, 0.f, 0.f, 0.f};
#pragma unroll
    for (int kk = 0; kk < 8; ++kk) {
        const short8 a0 = *(const short8*)&xs[m * 264 + kk * 32 + quad * 8];
        const short8 a1 = *(const short8*)&xs[(16 + m) * 264 + kk * 32 + quad * 8];
        acc0 = __builtin_amdgcn_mfma_f32_16x16x32_bf16(a0, bfrag[kk], acc0, 0, 0, 0);
        acc1 = __builtin_amdgcn_mfma_f32_16x16x32_bf16(a1, bfrag[kk], acc1, 0, 0, 0);
    }

    const int hhalf = s >> 1;               // feature half plane
    const int hcol = (s & 1) * 16 + m;      // column within the 32-wide plane
    ushort* __restrict__ hp = h + (size_t)hhalf * N_NODES * 32 + hcol;
#pragma unroll
    for (int r = 0; r < 4; ++r) {
        const int row0 = nbase + quad * 4 + r;
        const int row1 = row0 + 16;
        if (row0 < N_NODES) hp[(size_t)row0 * 32] = f2bf(acc0[r]);
        if (row1 < N_NODES) hp[(size_t)row1 * 32] = f2bf(acc1[r]);
    }
}

// ---------------- gather v3: feature-split, L2-resident h plane -------------
// Blocks [0,1563) do features 0-31, [1563,3126) features 32-63; in-order
// dispatch time-partitions the phases, so each XCD's L2 holds one 3.2MB plane
// (fits 4MiB) instead of thrashing 6.4MB. Rows are 64B; a wave reads 2 edges
// per load: lanes 0-31 even edge, 32-63 odd edge (v_cndmask on two readlane'd
// slot words). Weight = top 16 bits of slot word = f32 bit pattern. Lanes
// beyond deg carry slot 0 -> weight 0, no guards. Parity halves combined by
// one shfl_xor(32) per dst at the end.
__global__ __launch_bounds__(256) void gc_gather(const ushort* __restrict__ h,
                                                 const unsigned int* __restrict__ slots,
                                                 const int* __restrict__ cnt,
                                                 const float* __restrict__ bias,
                                                 float* __restrict__ out) {
    const int blk = blockIdx.x;
    const int half = (blk >= 1563) ? 1 : 0;
    const int grp = blk - half * 1563;
    const int w = threadIdx.x >> 6;
    const int l = threadIdx.x & 63;
    const int d0 = (grp * 4 + w) * 8;
    if (d0 >= N_NODES) return;  // 6250 live waves per half; last block idles 2

    const int4 ca = *(const int4*)(cnt + d0);
    const int4 cb = *(const int4*)(cnt + d0 + 4);
    const int dg0 = min(ca.x, CAP), dg1 = min(ca.y, CAP);
    const int dg2 = min(ca.z, CAP), dg3 = min(ca.w, CAP);
    const int dg4 = min(cb.x, CAP), dg5 = min(cb.y, CAP);
    const int dg6 = min(cb.z, CAP), dg7 = min(cb.w, CAP);
    const int mdeg = max(max(max(dg0, dg1), max(dg2, dg3)),
                         max(max(dg4, dg5), max(dg6, dg7)));

    const unsigned sw0 = (l < dg0) ? slots[(size_t)(d0 + 0) * CAP + l] : 0u;
    const unsigned sw1 = (l < dg1) ? slots[(size_t)(d0 + 1) * CAP + l] : 0u;
    const unsigned sw2 = (l < dg2) ? slots[(size_t)(d0 + 2) * CAP + l] : 0u;
    const unsigned sw3 = (l < dg3) ? slots[(size_t)(d0 + 3) * CAP + l] : 0u;
    const unsigned sw4 = (l < dg4) ? slots[(size_t)(d0 + 4) * CAP + l] : 0u;
    const unsigned sw5 = (l < dg5) ? slots[(size_t)(d0 + 5) * CAP + l] : 0u;
    const unsigned sw6 = (l < dg6) ? slots[(size_t)(d0 + 6) * CAP + l] : 0u;
    const unsigned sw7 = (l < dg7) ? slots[(size_t)(d0 + 7) * CAP + l] : 0u;

    const int hi = l >> 5;   // edge parity this lane serves
    const int c = l & 31;    // feature within the half-plane
    const ushort* __restrict__ hb = h + (size_t)half * N_NODES * 32 + c;

    float a0 = 0.f, a1 = 0.f, a2 = 0.f, a3 = 0.f;
    float a4 = 0.f, a5 = 0.f, a6 = 0.f, a7 = 0.f;

    for (int i0 = 0; i0 < mdeg; i0 += 8) {
#define PROC(sw, acc)                                                          \
    {                                                                          \
        unsigned q[4];                                                         \
        ushort hv[4];                                                          \
        _Pragma("unroll") for (int p = 0; p < 4; ++p)                          \
        {                                                                      \
            const int e = i0 + p * 2;                                          \
            const int qlo = __builtin_amdgcn_readlane((int)(sw), e);           \
            const int qhi = __builtin_amdgcn_readlane((int)(sw), e + 1);       \
            q[p] = (unsigned)(hi ? qhi : qlo);                                 \
            hv[p] = hb[(size_t)(q[p] & 0xFFFFu) * 32];                         \
        }                                                                      \
        _Pragma("unroll") for (int p = 0; p < 4; ++p)                          \
            acc = fmaf(__uint_as_float(q[p] & 0xFFFF0000u),                    \
                       __uint_as_float((unsigned)hv[p] << 16), acc);           \
    }
        PROC(sw0, a0)
        PROC(sw1, a1)
        PROC(sw2, a2)
        PROC(sw3, a3)
        PROC(sw4, a4)
        PROC(sw5, a5)
        PROC(sw6, a6)
        PROC(sw7, a7)
#undef PROC
    }

    // combine edge parities: lanes l and l^32 share feature c
    a0 += __shfl_xor(a0, 32); a1 += __shfl_xor(a1, 32);
    a2 += __shfl_xor(a2, 32); a3 += __shfl_xor(a3, 32);
    a4 += __shfl_xor(a4, 32); a5 += __shfl_xor(a5, 32);
    a6 += __shfl_xor(a6, 32); a7 += __shfl_xor(a7, 32);

    if (l < 32) {
        const float bf = bias[half * 32 + l];
        float* __restrict__ ob = out + half * 32 + l;
        ob[(size_t)(d0 + 0) * OUT_F] = a0 + bf;
        ob[(size_t)(d0 + 1) * OUT_F] = a1 + bf;
        ob[(size_t)(d0 + 2) * OUT_F] = a2 + bf;
        ob[(size_t)(d0 + 3) * OUT_F] = a3 + bf;
        ob[(size_t)(d0 + 4) * OUT_F] = a4 + bf;
        ob[(size_t)(d0 + 5) * OUT_F] = a5 + bf;
        ob[(size_t)(d0 + 6) * OUT_F] = a6 + bf;
        ob[(size_t)(d0 + 7) * OUT_F] = a7 + bf;
    }
}

extern "C" void kernel_launch(void* const* d_in, const int* in_sizes, int n_in,
                              void* d_out, int out_size, void* d_ws, size_t ws_size,
                              hipStream_t stream) {
    const float* x    = (const float*)d_in[0];
    const float* W    = (const float*)d_in[1];
    const float* bias = (const float*)d_in[2];
    const float* ew   = (const float*)d_in[3];
    const int* src    = (const int*)d_in[4];
    const int* dst    = (const int*)d_in[5];
    float* out = (float*)d_out;

    // workspace layout (16B-aligned) -- R7 layout
    char* ws = (char*)d_ws;
    ushort* h           = (ushort*)ws;                    // 6,400,000 B (2 planes)
    int* cnt            = (int*)(ws + 6400000);           // 200,000 B
    unsigned int* slots = (unsigned int*)(ws + 6600000);  // 12,800,000 B
    ushort* Wb          = (ushort*)(ws + 19400000);       // 32,768 B
    int* cursor         = (int*)(ws + 19432768);          // 512 B
    uint2* arena        = (uint2*)(ws + 19433280);        // 7,077,888 B

    gc_prep<<<8, 256, 0, stream>>>(W, Wb, cursor);
    gc_bucket<<<391, 256, 0, stream>>>(src, dst, ew, cursor, arena);
    gc_place2<<<NBKT, 512, 0, stream>>>(arena, cursor, cnt, slots);
    gc_gemm<<<1563, 256, 0, stream>>>(x, Wb, h);
    // feature-split gather: blocks [0,1563) half 0, [1563,3126) half 1
    gc_gather<<<3126, 256, 0, stream>>>(h, slots, cnt, bias, out);
}

// Round 12
// 141.446 us; speedup vs baseline: 2.7281x; 1.1209x over previous
//
#include <hip/hip_runtime.h>
#include <hip/hip_bf16.h>

#define N_NODES 50000
#define N_EDGES 800000
#define IN_F 256
#define OUT_F 64

#define CAP 64          // slot capacity per dst == wave width; max degree ~45
#define NBKT 256        // dst-range buckets == CU count
#define DST_PER_BKT 196 // ceil(50000/256); 196*256 = 50176
#define NPERM 50176     // perm index space (includes 176 invalid ids, deg 0)
#define BKT_CAP 3584    // mean 3125, sigma ~56 -> +8.2 sigma; multiple of 64

typedef __attribute__((ext_vector_type(8))) short short8;   // 8 bf16 (4 VGPRs)
typedef __attribute__((ext_vector_type(4))) float f32x4;    // MFMA acc

static __device__ __forceinline__ ushort f2bf(float v) {
    __hip_bfloat16 b = __float2bfloat16(v);
    return *(ushort*)&b;
}

// ---------------- prep: zero bucket cursors + W -> bf16 B-fragment order ----
__global__ __launch_bounds__(256) void gc_prep(const float* __restrict__ W,
                                               ushort* __restrict__ Wb,
                                               int* __restrict__ cursor) {
    const int g = blockIdx.x * 256 + threadIdx.x;  // 8 blocks -> g in [0,2048)
    if (g < NBKT) cursor[g] = 0;
    {
        const int s = g >> 9;
        const int kk = (g >> 6) & 7;
        const int lane = g & 63;
        const int n = s * 16 + (lane & 15);
        const int kb = kk * 32 + (lane >> 4) * 8;
#pragma unroll
        for (int j = 0; j < 8; ++j)
            Wb[(size_t)g * 8 + j] = f2bf(W[(kb + j) * OUT_F + n]);
    }
}

// ---------------- bucket: partition edges into 256 dst-range lists ----------
// (R7-proven shape) contiguous per-block runs -> no write amplification.
__global__ __launch_bounds__(256) void gc_bucket(const int* __restrict__ esrc,
                                                 const int* __restrict__ edst,
                                                 const float* __restrict__ ew,
                                                 int* __restrict__ cursor,
                                                 uint2* __restrict__ arena) {
    __shared__ int hist[NBKT];
    __shared__ int base[NBKT];
    const int t = threadIdx.x;
    hist[t] = 0;  // t in [0,256) == NBKT
    __syncthreads();

    const int e0 = blockIdx.x * 2048 + t * 8;  // 391 blocks; N_EDGES % 8 == 0
    const bool valid = e0 < N_EDGES;
    int b[8], loff[8];
    uint2 ent[8];
    if (valid) {
        const int4 sa = *(const int4*)(esrc + e0);
        const int4 sb = *(const int4*)(esrc + e0 + 4);
        const int4 da = *(const int4*)(edst + e0);
        const int4 db = *(const int4*)(edst + e0 + 4);
        const float4 wa = *(const float4*)(ew + e0);
        const float4 wb = *(const float4*)(ew + e0 + 4);
        const int ds[8] = {da.x, da.y, da.z, da.w, db.x, db.y, db.z, db.w};
        const int ss[8] = {sa.x, sa.y, sa.z, sa.w, sb.x, sb.y, sb.z, sb.w};
        const float wf[8] = {wa.x, wa.y, wa.z, wa.w, wb.x, wb.y, wb.z, wb.w};
#pragma unroll
        for (int j = 0; j < 8; ++j) {
            b[j] = ds[j] / DST_PER_BKT;  // exact magic-mul, max 255
            ent[j].x = (unsigned)ds[j];
            ent[j].y = ((unsigned)f2bf(wf[j]) << 16) | (unsigned)(ss[j] & 0xFFFF);
            loff[j] = atomicAdd(&hist[b[j]], 1);
        }
    }
    __syncthreads();
    {
        const int hc = hist[t];
        base[t] = hc ? atomicAdd(&cursor[t], hc) : 0;
    }
    __syncthreads();
    if (valid) {
#pragma unroll
        for (int j = 0; j < 8; ++j) {
            const int pos = base[b[j]] + loff[j];
            if (pos < BKT_CAP)
                arena[(size_t)b[j] * BKT_CAP + pos] = ent[j];
        }
    }
}

// ---------------- place2: one block per CU, LDS counting + degree-sort ------
// R7-proven LDS counting (zero fabric atomics) with two upgrades:
//  (a) NBKT 256 -> all CUs busy (R7 used 128 = half idle), 2-way batched
//      entry chains for MLP;
//  (b) emits a degree-sorted permutation per bucket (LDS counting sort over
//      degree 0..64) so gather can batch 8 similar-degree dsts -> mdeg ~= mean
//      degree instead of max-of-8 (~28 vs 16: kills ~40% wasted slots).
__global__ __launch_bounds__(512) void gc_place2(const uint2* __restrict__ arena,
                                                 const int* __restrict__ cursor,
                                                 int* __restrict__ cnt,
                                                 unsigned int* __restrict__ slots,
                                                 int* __restrict__ perm) {
    __shared__ int lcnt[DST_PER_BKT];
    __shared__ int dhist[CAP + 1];  // degree histogram / rank cursors, 0..64
    const int b = blockIdx.x;
    const int t = threadIdx.x;
    const int dbase = b * DST_PER_BKT;

    if (t < DST_PER_BKT) lcnt[t] = 0;
    if (t >= 512 - (CAP + 1)) dhist[t - (512 - (CAP + 1))] = 0;
    __syncthreads();

    const int n = min(cursor[b], BKT_CAP);
    const uint2* __restrict__ p = arena + (size_t)b * BKT_CAP;
    for (int i = t; i < n; i += 1024) {  // 2-way batch: i and i+512
        const uint2 e0 = p[i];
        const bool has1 = (i + 512) < n;
        uint2 e1 = {0u, 0u};
        if (has1) e1 = p[i + 512];
        const int pos0 = atomicAdd(&lcnt[e0.x - dbase], 1);
        if (pos0 < CAP) slots[(size_t)e0.x * CAP + pos0] = e0.y;
        if (has1) {
            const int pos1 = atomicAdd(&lcnt[e1.x - dbase], 1);
            if (pos1 < CAP) slots[(size_t)e1.x * CAP + pos1] = e1.y;
        }
    }
    __syncthreads();

    if (t < DST_PER_BKT) {
        const int d = dbase + t;
        if (d < N_NODES) cnt[d] = lcnt[t];
        atomicAdd(&dhist[min(lcnt[t], CAP)], 1);
    }
    __syncthreads();
    if (t == 0) {  // exclusive prefix over 65 bins (trivial)
        int run = 0;
#pragma unroll
        for (int k = 0; k <= CAP; ++k) { const int c = dhist[k]; dhist[k] = run; run += c; }
    }
    __syncthreads();
    if (t < DST_PER_BKT) {
        const int rank = atomicAdd(&dhist[min(lcnt[t], CAP)], 1);
        perm[dbase + rank] = dbase + t;
    }
}

// ---------------- gemm: 32-node MFMA tiles (R7 verbatim) --------------------
__global__ __launch_bounds__(256) void gc_gemm(const float* __restrict__ x,
                                               const ushort* __restrict__ Wb,
                                               ushort* __restrict__ h) {
    __shared__ ushort xs[32 * 264];  // 16896 B
    const int t = threadIdx.x;
    const int nbase = blockIdx.x * 32;

    {
#pragma unroll
        for (int i = 0; i < 8; ++i) {
            const int idx = t + i * 256;
            const int node = idx >> 6;
            const int c4 = idx & 63;
            int gnode = nbase + node;
            if (gnode >= N_NODES) gnode = N_NODES - 1;  // clamp tail loads
            const float4 v = ((const float4*)x)[(size_t)gnode * 64 + c4];
            ushort4 bv;
            bv.x = f2bf(v.x); bv.y = f2bf(v.y); bv.z = f2bf(v.z); bv.w = f2bf(v.w);
            *(ushort4*)&xs[node * 264 + c4 * 4] = bv;
        }
    }

    const int s = t >> 6;
    const int lane = t & 63;
    const int m = lane & 15;
    const int quad = lane >> 4;

    short8 bfrag[8];
#pragma unroll
    for (int kk = 0; kk < 8; ++kk)
        bfrag[kk] = *(const short8*)(Wb + ((size_t)(s * 8 + kk) * 64 + lane) * 8);

    __syncthreads();

    f32x4 acc0 = {0.f, 0.f, 0.f, 0.f};
    f32x4 acc1 = {0.f, 0.f, 0.f, 0.f};
#pragma unroll
    for (int kk = 0; kk < 8; ++kk) {
        const short8 a0 = *(const short8*)&xs[m * 264 + kk * 32 + quad * 8];
        const short8 a1 = *(const short8*)&xs[(16 + m) * 264 + kk * 32 + quad * 8];
        acc0 = __builtin_amdgcn_mfma_f32_16x16x32_bf16(a0, bfrag[kk], acc0, 0, 0, 0);
        acc1 = __builtin_amdgcn_mfma_f32_16x16x32_bf16(a1, bfrag[kk], acc1, 0, 0, 0);
    }

#pragma unroll
    for (int r = 0; r < 4; ++r) {
        const int row0 = nbase + quad * 4 + r;
        const int row1 = row0 + 16;
        if (row0 < N_NODES) h[(size_t)row0 * OUT_F + s * 16 + m] = f2bf(acc0[r]);
        if (row1 < N_NODES) h[(size_t)row1 * OUT_F + s * 16 + m] = f2bf(acc1[r]);
    }
}

// ---------------- gather: 8 SIMILAR-DEGREE dsts/wave via perm ---------------
// R7-v1 structure (the fastest measured: SALU addressing, weight in SGPR,
// 2 VALU/edge, VALUBusy 28%) with dsts taken from the degree-sorted perm so
// mdeg ~= mean degree. Lanes >= deg carry slot 0 -> weight 0, no guards; out
// rows scattered by perm (full 256B rows, cheap). Invalid ids (>= N_NODES,
// always deg 0) skip the store.
__global__ __launch_bounds__(256) void gc_gather(const ushort* __restrict__ h,
                                                 const unsigned int* __restrict__ slots,
                                                 const int* __restrict__ cnt,
                                                 const int* __restrict__ perm,
                                                 const float* __restrict__ bias,
                                                 float* __restrict__ out) {
    const int wid = (blockIdx.x * 256 + threadIdx.x) >> 6;
    const int l = threadIdx.x & 63;
    const int base = wid * 8;  // 1568 blocks * 4 waves * 8 = 50176 = NPERM exact

    // lanes 0..7 fetch the wave's 8 perm'd dsts + degrees; broadcast via readlane
    int pdv = 0, dgv = 0;
    if (l < 8) {
        pdv = perm[base + l];
        dgv = (pdv < N_NODES) ? min(cnt[pdv], CAP) : 0;
    }
    const int pd0 = __builtin_amdgcn_readlane(pdv, 0);
    const int pd1 = __builtin_amdgcn_readlane(pdv, 1);
    const int pd2 = __builtin_amdgcn_readlane(pdv, 2);
    const int pd3 = __builtin_amdgcn_readlane(pdv, 3);
    const int pd4 = __builtin_amdgcn_readlane(pdv, 4);
    const int pd5 = __builtin_amdgcn_readlane(pdv, 5);
    const int pd6 = __builtin_amdgcn_readlane(pdv, 6);
    const int pd7 = __builtin_amdgcn_readlane(pdv, 7);
    const int dg0 = __builtin_amdgcn_readlane(dgv, 0);
    const int dg1 = __builtin_amdgcn_readlane(dgv, 1);
    const int dg2 = __builtin_amdgcn_readlane(dgv, 2);
    const int dg3 = __builtin_amdgcn_readlane(dgv, 3);
    const int dg4 = __builtin_amdgcn_readlane(dgv, 4);
    const int dg5 = __builtin_amdgcn_readlane(dgv, 5);
    const int dg6 = __builtin_amdgcn_readlane(dgv, 6);
    const int dg7 = __builtin_amdgcn_readlane(dgv, 7);
    const int mdeg = max(max(max(dg0, dg1), max(dg2, dg3)),
                         max(max(dg4, dg5), max(dg6, dg7)));

    const unsigned sw0 = (l < dg0) ? slots[(size_t)pd0 * CAP + l] : 0u;
    const unsigned sw1 = (l < dg1) ? slots[(size_t)pd1 * CAP + l] : 0u;
    const unsigned sw2 = (l < dg2) ? slots[(size_t)pd2 * CAP + l] : 0u;
    const unsigned sw3 = (l < dg3) ? slots[(size_t)pd3 * CAP + l] : 0u;
    const unsigned sw4 = (l < dg4) ? slots[(size_t)pd4 * CAP + l] : 0u;
    const unsigned sw5 = (l < dg5) ? slots[(size_t)pd5 * CAP + l] : 0u;
    const unsigned sw6 = (l < dg6) ? slots[(size_t)pd6 * CAP + l] : 0u;
    const unsigned sw7 = (l < dg7) ? slots[(size_t)pd7 * CAP + l] : 0u;

    const float bf = bias[l];
    float a0 = bf, a1 = bf, a2 = bf, a3 = bf, a4 = bf, a5 = bf, a6 = bf, a7 = bf;

    const ushort* __restrict__ hf = h + l;

#define ROWLD(sw, ll) \
    hf[(size_t)((unsigned)__builtin_amdgcn_readlane((int)(sw), (ll)) & 0xFFFFu) * OUT_F]
#define WBITS(sw, ll) \
    __uint_as_float((unsigned)__builtin_amdgcn_readlane((int)(sw), (ll)) & 0xFFFF0000u)

    for (int i0 = 0; i0 < mdeg; i0 += 8) {
        unsigned hv0[8], hv1[8], hv2[8], hv3[8], hv4[8], hv5[8], hv6[8], hv7[8];
#pragma unroll
        for (int j = 0; j < 8; ++j) {
            const int ll = i0 + j;  // uniform, <= 63
            hv0[j] = ROWLD(sw0, ll);
            hv1[j] = ROWLD(sw1, ll);
            hv2[j] = ROWLD(sw2, ll);
            hv3[j] = ROWLD(sw3, ll);
            hv4[j] = ROWLD(sw4, ll);
            hv5[j] = ROWLD(sw5, ll);
            hv6[j] = ROWLD(sw6, ll);
            hv7[j] = ROWLD(sw7, ll);
        }
#pragma unroll
        for (int j = 0; j < 8; ++j) {
            const int ll = i0 + j;
            a0 += WBITS(sw0, ll) * __uint_as_float(hv0[j] << 16);
            a1 += WBITS(sw1, ll) * __uint_as_float(hv1[j] << 16);
            a2 += WBITS(sw2, ll) * __uint_as_float(hv2[j] << 16);
            a3 += WBITS(sw3, ll) * __uint_as_float(hv3[j] << 16);
            a4 += WBITS(sw4, ll) * __uint_as_float(hv4[j] << 16);
            a5 += WBITS(sw5, ll) * __uint_as_float(hv5[j] << 16);
            a6 += WBITS(sw6, ll) * __uint_as_float(hv6[j] << 16);
            a7 += WBITS(sw7, ll) * __uint_as_float(hv7[j] << 16);
        }
    }
#undef ROWLD
#undef WBITS

    if (pd0 < N_NODES) out[(size_t)pd0 * OUT_F + l] = a0;
    if (pd1 < N_NODES) out[(size_t)pd1 * OUT_F + l] = a1;
    if (pd2 < N_NODES) out[(size_t)pd2 * OUT_F + l] = a2;
    if (pd3 < N_NODES) out[(size_t)pd3 * OUT_F + l] = a3;
    if (pd4 < N_NODES) out[(size_t)pd4 * OUT_F + l] = a4;
    if (pd5 < N_NODES) out[(size_t)pd5 * OUT_F + l] = a5;
    if (pd6 < N_NODES) out[(size_t)pd6 * OUT_F + l] = a6;
    if (pd7 < N_NODES) out[(size_t)pd7 * OUT_F + l] = a7;
}

extern "C" void kernel_launch(void* const* d_in, const int* in_sizes, int n_in,
                              void* d_out, int out_size, void* d_ws, size_t ws_size,
                              hipStream_t stream) {
    const float* x    = (const float*)d_in[0];
    const float* W    = (const float*)d_in[1];
    const float* bias = (const float*)d_in[2];
    const float* ew   = (const float*)d_in[3];
    const int* src    = (const int*)d_in[4];
    const int* dst    = (const int*)d_in[5];
    float* out = (float*)d_out;

    // workspace layout (16B-aligned)
    char* ws = (char*)d_ws;
    ushort* h           = (ushort*)ws;                    // 6,400,000 B
    int* cnt            = (int*)(ws + 6400000);           // 200,000 B
    unsigned int* slots = (unsigned int*)(ws + 6600000);  // 12,800,000 B
    ushort* Wb          = (ushort*)(ws + 19400000);       // 32,768 B
    int* cursor         = (int*)(ws + 19432768);          // 1,024 B
    int* perm           = (int*)(ws + 19433792);          // 200,704 B
    uint2* arena        = (uint2*)(ws + 19634496);        // 7,340,032 B

    gc_prep<<<8, 256, 0, stream>>>(W, Wb, cursor);
    gc_bucket<<<391, 256, 0, stream>>>(src, dst, ew, cursor, arena);
    gc_place2<<<NBKT, 512, 0, stream>>>(arena, cursor, cnt, slots, perm);
    gc_gemm<<<1563, 256, 0, stream>>>(x, Wb, h);
    // 8 similar-degree dsts per wave via perm; 1568 blocks * 32 = 50176 exact
    gc_gather<<<1568, 256, 0, stream>>>(h, slots, cnt, perm, bias, out);
}